// Round 8
// baseline (291.021 us; speedup 1.0000x reference)
//
#include <hip/hip_runtime.h>
#include <math.h>

#define NV 778
#define KROW 2334     // NV*3
#define KTOT 146      // 10 beta + 135 pose-feature + 1 const(template)
#define NCOL 1008     // 21 j * 16 jj * 3 c
#define NSTORE 12     // stored v-partials
#define VSP2 65       // v per PKpart block (12*65=780 >= 778)

// ======================= kT: transpose dirsX -> dirsXT[2334][146] ============
__global__ __launch_bounds__(256) void kT(const float* __restrict__ shapedirs,
                                          const float* __restrict__ posedirs,
                                          const float* __restrict__ v_template,
                                          float* __restrict__ dirsXT)
{
    __shared__ float tl[64][65];
    const int bx = blockIdx.x % 37;
    const int bk = blockIdx.x / 37;
    const int x0 = bx*64, k0 = bk*64;
    const int tx = threadIdx.x & 63, ty = threadIdx.x >> 6;
#pragma unroll 4
    for (int i = 0; i < 16; ++i) {
        const int r = ty*16 + i;
        const int kk = k0 + r, xx = x0 + tx;
        if (kk < KTOT && xx < KROW) {
            const float* drow = (kk < 10)  ? shapedirs + (size_t)kk*KROW
                              : (kk < 145) ? posedirs + (size_t)(kk-10)*KROW
                                           : v_template;
            tl[r][tx] = drow[xx];
        }
    }
    __syncthreads();
#pragma unroll 4
    for (int i = 0; i < 16; ++i) {
        const int xr = ty*16 + i;
        const int xx = x0 + xr, kk = k0 + tx;
        if (xx < KROW && kk < KTOT)
            dirsXT[(size_t)xx*KTOT + kk] = tl[tx][xr];
    }
}

// ======================= kSQ: SJ/J0 (v-split + atomics) and Q ================
// bid < 384 : (j,c,s): partial SJ[k][j][c], J0[j][c] over v in [s*98, s*98+98)
//             -> wave-reduce -> atomicAdd (SJ/J0/Q region pre-zeroed by memset)
// bid < 390 : Q[j*16+jj], lane = global m, full v loop, direct write
__global__ __launch_bounds__(64) void kSQ(const float* __restrict__ shapedirs,
                                          const float* __restrict__ v_template,
                                          const float* __restrict__ Jreg,
                                          const float* __restrict__ wgt,
                                          float* __restrict__ SJ, float* __restrict__ J0,
                                          float* __restrict__ Q)
{
    const int bid = blockIdx.x;
    const int t = threadIdx.x;
    if (bid < 384) {
        const int s  = bid & 7;
        const int jc = bid >> 3;          // 0..47
        const int j = jc / 3, c = jc % 3;
        const int v0 = s*98, v1 = min(NV, v0 + 98);
        float acc[11];
#pragma unroll
        for (int k = 0; k < 11; ++k) acc[k] = 0.f;
        for (int v = v0 + t; v < v1; v += 64) {
            const float jr = Jreg[v*21 + j];
            acc[10] += v_template[v*3 + c] * jr;
#pragma unroll
            for (int k = 0; k < 10; ++k)
                acc[k] += shapedirs[(size_t)k*KROW + v*3 + c] * jr;
        }
#pragma unroll
        for (int k = 0; k < 11; ++k) {
            float x = acc[k];
#pragma unroll
            for (int off = 32; off >= 1; off >>= 1) x += __shfl_down(x, off, 64);
            acc[k] = x;
        }
        if (t == 0) {
#pragma unroll
            for (int k = 0; k < 10; ++k) atomicAdd(&SJ[k*48 + j*3 + c], acc[k]);
            atomicAdd(&J0[j*3 + c], acc[10]);
        }
    } else {
        const int m = (bid - 384)*64 + t;
        if (m < 336) {
            const int j = m >> 4, jj = m & 15;
            float s = 0.f;
#pragma unroll 4
            for (int v = 0; v < NV; ++v)
                s += Jreg[v*21 + j] * wgt[v*16 + jj];
            Q[m] = s;
        }
    }
}

// ======================= k_pre: PKpart only ==================================
// 504 blocks (j, h, s): PKpart[s][k][j*48 + h*24 + jjj*3 + c]
__global__ __launch_bounds__(192) void k_pre(const float* __restrict__ dirsXT,
                                             const float* __restrict__ Jreg,
                                             const float* __restrict__ wgt,
                                             float* __restrict__ PKpart)
{
    __shared__ float w2h[VSP2*8];     // 2 KB
    const int pb = blockIdx.x;           // 0..503
    const int t = threadIdx.x;
    const int j  = pb % 21;
    const int h  = (pb / 21) & 1;        // jj half
    const int s  = pb / 42;              // 0..11
    const int v0 = s*VSP2;
    const int nvv = min(VSP2, NV - v0);

    for (int idx = t; idx < nvv*8; idx += 192) {
        const int vv = idx >> 3, jjj = idx & 7;
        w2h[idx] = Jreg[(size_t)(v0+vv)*21 + j] * wgt[(size_t)(v0+vv)*16 + h*8 + jjj];
    }
    __syncthreads();

    if (t < KTOT) {
        float acc[24];
#pragma unroll
        for (int q = 0; q < 24; ++q) acc[q] = 0.f;
        const float* dcol = dirsXT + t;
#pragma unroll 2
        for (int vv = 0; vv < nvv; ++vv) {
            const size_t xb = (size_t)3*(v0+vv)*KTOT;
            const float d0 = dcol[xb];
            const float d1 = dcol[xb + KTOT];
            const float d2 = dcol[xb + 2*KTOT];
            const float4 wa = *(const float4*)(w2h + vv*8);      // broadcast
            const float4 wb = *(const float4*)(w2h + vv*8 + 4);
            const float w[8] = {wa.x,wa.y,wa.z,wa.w, wb.x,wb.y,wb.z,wb.w};
#pragma unroll
            for (int q = 0; q < 8; ++q) {
                acc[q*3+0] += d0*w[q];
                acc[q*3+1] += d1*w[q];
                acc[q*3+2] += d2*w[q];
            }
        }
        float4* o = (float4*)(PKpart + ((size_t)s*KTOT + t)*NCOL + j*48 + h*24);
#pragma unroll
        for (int q = 0; q < 6; ++q)
            o[q] = make_float4(acc[4*q+0], acc[4*q+1], acc[4*q+2], acc[4*q+3]);
    }
}

// ======================= k_p3: reduce partials -> PK[146][1008] ==============
__global__ void k_p3(const float* __restrict__ PKpart, float* __restrict__ PK)
{
    const int idx = blockIdx.x*256 + threadIdx.x;
    if (idx < KTOT*NCOL) {
        float acc = 0.f;
#pragma unroll
        for (int s = 0; s < NSTORE; ++s)
            acc += PKpart[(size_t)s*KTOT*NCOL + idx];
        PK[idx] = acc;
    }
}

// ======================= k2: rodrigues + coefT + kinematic chain =============
__global__ __launch_bounds__(256) void k2_pose(const float* __restrict__ beta,
                                               const float* __restrict__ theta,
                                               const float* __restrict__ wrist,
                                               const float* __restrict__ hc,
                                               const float* __restrict__ hm,
                                               const float* __restrict__ SJ,
                                               const float* __restrict__ J0,
                                               float* __restrict__ coefT,
                                               float* __restrict__ A_g, int B, int cstride)
{
    __shared__ float Rs[16*144];
    __shared__ float cls[16*148];
    __shared__ float SJs[480];
    __shared__ float J0s[48];
    const int t = threadIdx.x;
    const int bl = t >> 4, i = t & 15;
    const int b = blockIdx.x*16 + bl;

    for (int idx = t; idx < 480; idx += 256) SJs[idx] = SJ[idx];
    if (t < 48) J0s[t] = J0[t];

    float r0, r1, r2;
    if (i == 0) {
        r0 = wrist[b*3+0]; r1 = wrist[b*3+1]; r2 = wrist[b*3+2];
#pragma unroll
        for (int k = 0; k < 10; ++k) cls[bl*148 + k] = beta[b*10 + k];
        cls[bl*148 + 145] = 1.0f;
    } else {
        const int col = (i-1)*3;
        float e0 = hm[col], e1 = hm[col+1], e2 = hm[col+2];
#pragma unroll
        for (int k = 0; k < 10; ++k) {
            const float th = theta[b*10 + k];
            e0 += th * hc[k*45 + col];
            e1 += th * hc[k*45 + col+1];
            e2 += th * hc[k*45 + col+2];
        }
        r0 = e0; r1 = e1; r2 = e2;
    }
    const float x_ = r0 + 1e-8f, y_ = r1 + 1e-8f, z_ = r2 + 1e-8f;
    const float angle = sqrtf(x_*x_ + y_*y_ + z_*z_);
    const float inv = 1.0f / angle;
    const float x = r0*inv, y = r1*inv, z = r2*inv;
    const float sn = sinf(angle), cs = cosf(angle);
    const float t1 = 1.0f - cs;
    float R[9];
    R[0] = 1.f - t1*(y*y + z*z);
    R[1] = -sn*z + t1*x*y;
    R[2] =  sn*y + t1*x*z;
    R[3] =  sn*z + t1*x*y;
    R[4] = 1.f - t1*(x*x + z*z);
    R[5] = -sn*x + t1*y*z;
    R[6] = -sn*y + t1*x*z;
    R[7] =  sn*x + t1*y*z;
    R[8] = 1.f - t1*(x*x + y*y);
#pragma unroll
    for (int q = 0; q < 9; ++q) Rs[bl*144 + i*9 + q] = R[q];
    if (i > 0) {
#pragma unroll
        for (int q = 0; q < 9; ++q)
            cls[bl*148 + 10 + (i-1)*9 + q] = R[q] - ((q==0||q==4||q==8) ? 1.f : 0.f);
    }
    __syncthreads();

    if (t < KTOT) {
        float tmp[16];
#pragma unroll
        for (int m = 0; m < 16; ++m) tmp[m] = cls[m*148 + t];
        float4* dst = (float4*)(coefT + (size_t)t*cstride + blockIdx.x*16);
        dst[0] = make_float4(tmp[0],  tmp[1],  tmp[2],  tmp[3]);
        dst[1] = make_float4(tmp[4],  tmp[5],  tmp[6],  tmp[7]);
        dst[2] = make_float4(tmp[8],  tmp[9],  tmp[10], tmp[11]);
        dst[3] = make_float4(tmp[12], tmp[13], tmp[14], tmp[15]);
    }

    if (t < 16) {
        const int b2 = blockIdx.x*16 + t;
        float bt[10];
#pragma unroll
        for (int k = 0; k < 10; ++k) bt[k] = beta[b2*10 + k];
        const float* Rb = Rs + t*144;
        float4* Ab = (float4*)(A_g + (size_t)b2*192);

        auto jointJ = [&](int j, float* o) {
            float j0 = J0s[j*3+0], j1 = J0s[j*3+1], j2 = J0s[j*3+2];
#pragma unroll
            for (int k = 0; k < 10; ++k) {
                j0 += bt[k] * SJs[k*48 + j*3 + 0];
                j1 += bt[k] * SJs[k*48 + j*3 + 1];
                j2 += bt[k] * SJs[k*48 + j*3 + 2];
            }
            o[0] = j0; o[1] = j1; o[2] = j2;
        };

        float G0R[9], J0v[3];
#pragma unroll
        for (int q = 0; q < 9; ++q) G0R[q] = Rb[q];
        jointJ(0, J0v);
#pragma unroll
        for (int r = 0; r < 3; ++r) {
            const float at = J0v[r] - (G0R[r*3+0]*J0v[0] + G0R[r*3+1]*J0v[1] + G0R[r*3+2]*J0v[2]);
            Ab[r] = make_float4(G0R[r*3+0], G0R[r*3+1], G0R[r*3+2], at);
        }
        for (int ch = 0; ch < 5; ++ch) {
            float GpR[9], Gpt[3], Jp[3];
#pragma unroll
            for (int q = 0; q < 9; ++q) GpR[q] = G0R[q];
            Gpt[0]=J0v[0]; Gpt[1]=J0v[1]; Gpt[2]=J0v[2];
            Jp[0]=J0v[0];  Jp[1]=J0v[1];  Jp[2]=J0v[2];
            for (int s = 0; s < 3; ++s) {
                const int j = ch*3 + 1 + s;
                float Rl[9];
                const float* Rj = Rb + j*9;
#pragma unroll
                for (int q = 0; q < 9; ++q) Rl[q] = Rj[q];
                float Jc[3];
                jointJ(j, Jc);
                const float tl0 = Jc[0]-Jp[0], tl1 = Jc[1]-Jp[1], tl2 = Jc[2]-Jp[2];
                float GR[9], Gt[3];
#pragma unroll
                for (int r = 0; r < 3; ++r) {
#pragma unroll
                    for (int cc = 0; cc < 3; ++cc)
                        GR[r*3+cc] = GpR[r*3+0]*Rl[0*3+cc] + GpR[r*3+1]*Rl[1*3+cc] + GpR[r*3+2]*Rl[2*3+cc];
                    Gt[r] = GpR[r*3+0]*tl0 + GpR[r*3+1]*tl1 + GpR[r*3+2]*tl2 + Gpt[r];
                }
#pragma unroll
                for (int r = 0; r < 3; ++r) {
                    const float at = Gt[r] - (GR[r*3+0]*Jc[0] + GR[r*3+1]*Jc[1] + GR[r*3+2]*Jc[2]);
                    Ab[j*3 + r] = make_float4(GR[r*3+0], GR[r*3+1], GR[r*3+2], at);
                }
#pragma unroll
                for (int q = 0; q < 9; ++q) GpR[q] = GR[q];
                Gpt[0]=Gt[0]; Gpt[1]=Gt[1]; Gpt[2]=Gt[2];
                Jp[0]=Jc[0];  Jp[1]=Jc[1];  Jp[2]=Jc[2];
            }
        }
    }
}

// ======================= k3: P-GEMM + fused joint epilogue ===================
// 256 thr, grid (B/256, 21). Wave qg owns cols [12qg,12qg+12); thread owns 4
// batches. Distance-2 register prefetch on coef hides VMEM latency behind the
// 2x96-cyc FMA blocks. pex aliases pks (barrier-separated) -> 28 KB LDS.
__global__ __launch_bounds__(256) void k3_gemm(const float* __restrict__ coefT,
                                               const float* __restrict__ PK,
                                               const float* __restrict__ A_g,
                                               const float* __restrict__ Q,
                                               float* __restrict__ out, int B, int cstride)
{
    __shared__ float smem[KTOT*48];      // pks; re-used as pex after K-loop
    const int t  = threadIdx.x;
    const int b0 = blockIdx.x * 256;
    const int j  = blockIdx.y;
    const int qg = t >> 6;
    const int lg = t & 63;

    for (int idx = t; idx < KTOT*48; idx += 256) {
        const int k = idx / 48, x = idx - k*48;
        smem[idx] = PK[(size_t)k*NCOL + j*48 + x];
    }
    __syncthreads();

    float acc[4][12];
#pragma unroll
    for (int bi = 0; bi < 4; ++bi)
#pragma unroll
        for (int r = 0; r < 12; ++r) acc[bi][r] = 0.f;

    const float* cb = coefT + b0 + lg;
    const float* pw = smem + 12*qg;

    float ca[4], cbv[4];
#pragma unroll
    for (int q = 0; q < 4; ++q) {
        ca[q]  = cb[64*q];
        cbv[q] = cb[(size_t)cstride + 64*q];
    }

    for (int k = 0; k < KTOT; k += 2) {
        const int kp2 = (k+2 < KTOT) ? k+2 : KTOT-1;
        const int kp3 = (k+3 < KTOT) ? k+3 : KTOT-1;
        float cc[4], cd[4];
#pragma unroll
        for (int q = 0; q < 4; ++q) {
            cc[q] = cb[(size_t)kp2*cstride + 64*q];
            cd[q] = cb[(size_t)kp3*cstride + 64*q];
        }
        const float4 p0 = *(const float4*)(pw + k*48);
        const float4 p1 = *(const float4*)(pw + k*48 + 4);
        const float4 p2 = *(const float4*)(pw + k*48 + 8);
        const float4 q0 = *(const float4*)(pw + (k+1)*48);
        const float4 q1 = *(const float4*)(pw + (k+1)*48 + 4);
        const float4 q2 = *(const float4*)(pw + (k+1)*48 + 8);
        const float p[12] = {p0.x,p0.y,p0.z,p0.w, p1.x,p1.y,p1.z,p1.w, p2.x,p2.y,p2.z,p2.w};
        const float qv[12] = {q0.x,q0.y,q0.z,q0.w, q1.x,q1.y,q1.z,q1.w, q2.x,q2.y,q2.z,q2.w};
#pragma unroll
        for (int r = 0; r < 12; ++r) {
            acc[0][r] += p[r]*ca[0];
            acc[1][r] += p[r]*ca[1];
            acc[2][r] += p[r]*ca[2];
            acc[3][r] += p[r]*ca[3];
        }
#pragma unroll
        for (int r = 0; r < 12; ++r) {
            acc[0][r] += qv[r]*cbv[0];
            acc[1][r] += qv[r]*cbv[1];
            acc[2][r] += qv[r]*cbv[2];
            acc[3][r] += qv[r]*cbv[3];
        }
#pragma unroll
        for (int q = 0; q < 4; ++q) { ca[q] = cc[q]; cbv[q] = cd[q]; }
    }

    __syncthreads();   // all pks reads done; smem becomes pex

    const float* Qj = Q + j*16 + 4*qg;
#pragma unroll
    for (int bi = 0; bi < 4; ++bi) {
        const int b = b0 + lg + 64*bi;
        const float4* Ab = ((const float4*)A_g) + (size_t)b*48 + 12*qg;
        float jx = 0.f, jy = 0.f, jz = 0.f;
#pragma unroll
        for (int l = 0; l < 4; ++l) {
            const float4 a0 = Ab[l*3+0];
            const float4 a1 = Ab[l*3+1];
            const float4 a2 = Ab[l*3+2];
            const float qq = Qj[l];
            const float px = acc[bi][l*3+0], py = acc[bi][l*3+1], pz = acc[bi][l*3+2];
            jx += a0.x*px + a0.y*py + a0.z*pz + a0.w*qq;
            jy += a1.x*px + a1.y*py + a1.z*pz + a1.w*qq;
            jz += a2.x*px + a2.y*py + a2.z*pz + a2.w*qq;
        }
        const int bloc = lg + 64*bi;
        smem[bloc*13 + qg*3 + 0] = jx;
        smem[bloc*13 + qg*3 + 1] = jy;
        smem[bloc*13 + qg*3 + 2] = jz;
    }
    __syncthreads();

    {
        const float* pr = smem + t*13;
        const float jx = pr[0] + pr[3] + pr[6] + pr[9];
        const float jy = pr[1] + pr[4] + pr[7] + pr[10];
        const float jz = pr[2] + pr[5] + pr[8] + pr[11];
        float* op = out + (size_t)(b0 + t)*63 + j*3;
        op[0] = jx; op[1] = jy; op[2] = jz;
    }
}

// ============================================================================
extern "C" void kernel_launch(void* const* d_in, const int* in_sizes, int n_in,
                              void* d_out, int out_size, void* d_ws, size_t ws_size,
                              hipStream_t stream) {
    (void)n_in; (void)out_size; (void)ws_size;
    const float* beta       = (const float*)d_in[0];
    const float* theta      = (const float*)d_in[1];
    const float* wrist      = (const float*)d_in[2];
    const float* v_template = (const float*)d_in[3];
    const float* shapedirs  = (const float*)d_in[4];
    const float* posedirs   = (const float*)d_in[5];
    const float* Jreg       = (const float*)d_in[6];
    const float* hc         = (const float*)d_in[7];
    const float* hm         = (const float*)d_in[8];
    const float* wgt        = (const float*)d_in[9];
    float* out = (float*)d_out;
    const int B = in_sizes[0] / 10;
    const int cstride = B + 64;

    float* ws = (float*)d_ws;
    size_t off = 0;
    auto alloc = [&](size_t n) { float* p = ws + off; off = (off + n + 63) & ~(size_t)63; return p; };
    float* SJ     = alloc(480);
    float* J0     = alloc(48);
    float* Q      = alloc(336);
    float* dirsXT = alloc((size_t)KROW*KTOT);
    float* PKpart = alloc((size_t)NSTORE*KTOT*NCOL);
    float* PK     = alloc((size_t)KTOT*NCOL);
    float* coefT  = alloc((size_t)KTOT*cstride);
    float* A_g    = alloc((size_t)B*192);

    // zero SJ/J0/Q region (floats [0, 912) of ws) for the atomic accumulation
    hipMemsetAsync(d_ws, 0, 912*sizeof(float), stream);

    kT<<<111, 256, 0, stream>>>(shapedirs, posedirs, v_template, dirsXT);
    kSQ<<<390, 64, 0, stream>>>(shapedirs, v_template, Jreg, wgt, SJ, J0, Q);
    k_pre<<<21*2*NSTORE, 192, 0, stream>>>(dirsXT, Jreg, wgt, PKpart);
    k2_pose<<<(B + 15)/16, 256, 0, stream>>>(beta, theta, wrist, hc, hm, SJ, J0,
                                             coefT, A_g, B, cstride);
    k_p3<<<(KTOT*NCOL + 255)/256, 256, 0, stream>>>(PKpart, PK);
    k3_gemm<<<dim3(B/256, 21), 256, 0, stream>>>(coefT, PK, A_g, Q, out, B, cstride);
}